// Round 5
// baseline (262.449 us; speedup 1.0000x reference)
//
#include <hip/hip_runtime.h>
#include <hip/hip_bf16.h>
#include <stdint.h>

#define DM 1024
#define DF 2048
#define NTOK 8192

typedef float f32x4 __attribute__((ext_vector_type(4)));
typedef short s16x8 __attribute__((ext_vector_type(8)));   // 8 bf16 in 4 VGPRs

__device__ __forceinline__ unsigned short f2bf(float f) {
    union { float f; unsigned int u; } v; v.f = f;
    unsigned int r = v.u + 0x7fffu + ((v.u >> 16) & 1u);   // RNE
    return (unsigned short)(r >> 16);
}

// async global->LDS, 16B per lane (1 KB per wave-instr). Dest is wave-uniform base
// + lane*16 (HW rule); source address is per-lane (pre-swizzled there).
__device__ __forceinline__ void gll16(const unsigned short* g, unsigned short* l) {
    __builtin_amdgcn_global_load_lds(
        (const __attribute__((address_space(1))) void*)g,
        (__attribute__((address_space(3))) void*)l, 16, 0, 0);
}

// ---------------- kernel 1a: w1/w2 fp32 [k][n] -> bf16 [n][k] (experts {0,1}) ----------------
__global__ __launch_bounds__(256) void wcvt_kernel(const float* __restrict__ w1,
                                                   const float* __restrict__ w2,
                                                   unsigned short* __restrict__ w1t,
                                                   unsigned short* __restrict__ w2t) {
    __shared__ __align__(16) unsigned short tl[64 * 66];     // 8448 B
    const int b = blockIdx.x;
    const int z = b >> 9;             // 0,1: w1 e0/e1 ; 2,3: w2 e0/e1
    const int rem = b & 511;
    const int e = z & 1, is2 = z >> 1;
    const int R = is2 ? DF : DM;      // src rows (k)  == dst row stride
    const int C = is2 ? DM : DF;      // src cols (n)
    const int by = is2 ? (rem >> 4) : (rem >> 5);
    const int bx = is2 ? (rem & 15) : (rem & 31);
    const int r0 = by * 64, c0 = bx * 64;
    const float* src = is2 ? (w2 + (size_t)e * DF * DM) : (w1 + (size_t)e * DM * DF);
    unsigned short* dst = is2 ? (w2t + (size_t)e * DM * DF) : (w1t + (size_t)e * DM * DF);
    const int t = threadIdx.x;
    const int tr = t >> 4;            // 0..15
    const int tc4 = (t & 15) * 4;     // col base (float4 granularity)
#pragma unroll
    for (int i = 0; i < 4; ++i) {
        const int r = tr + 16 * i;
        const float4 v = *(const float4*)&src[(size_t)(r0 + r) * C + (c0 + tc4)];
        const unsigned int wa = (unsigned int)f2bf(v.x) | ((unsigned int)f2bf(v.y) << 16);
        const unsigned int wb = (unsigned int)f2bf(v.z) | ((unsigned int)f2bf(v.w) << 16);
        *(unsigned int*)&tl[r * 66 + tc4]     = wa;
        *(unsigned int*)&tl[r * 66 + tc4 + 2] = wb;
    }
    __syncthreads();
#pragma unroll
    for (int i = 0; i < 2; ++i) {
        const int p = t + 256 * i;    // 512 output uint4 per tile
        const int cp = p >> 3;        // dst row (= src col), 0..63
        const int rc = p & 7;         // dst 8-col chunk (= src row block)
        unsigned int wds[4];
#pragma unroll
        for (int j = 0; j < 4; ++j) {
            const unsigned short a  = tl[(8 * rc + 2 * j)     * 66 + cp];
            const unsigned short bb = tl[(8 * rc + 2 * j + 1) * 66 + cp];
            wds[j] = (unsigned int)a | ((unsigned int)bb << 16);
        }
        *(uint4*)&dst[(size_t)(c0 + cp) * R + (r0 + 8 * rc)] = *(const uint4*)wds;
    }
}

// ---------------- kernel 1b: gating + zero-out + selective x->bf16 ----------------
__global__ __launch_bounds__(256) void gate_kernel(const float* __restrict__ x,
                                                   const float* __restrict__ gw,
                                                   const float* __restrict__ gb,
                                                   unsigned short* __restrict__ xb,
                                                   float* __restrict__ out,
                                                   int* __restrict__ counts,
                                                   int* __restrict__ lists,
                                                   float* __restrict__ sls) {
    __shared__ float gwT[8192];                     // gwT[e*1024 + d], 32 KB
    const int tid = threadIdx.x;
    {   // gw [1024][8] fp32 -> gwT[e][d]; coalesced float4 loads, 2-way-free scatter
        const float4* g4 = (const float4*)gw;       // 2048 float4
#pragma unroll
        for (int i = 0; i < 8; ++i) {
            const int q = tid + 256 * i;
            const float4 v = g4[q];
            const int d = q >> 1, eb = 4 * (q & 1);
            gwT[(eb + 0) * 1024 + d] = v.x;
            gwT[(eb + 1) * 1024 + d] = v.y;
            gwT[(eb + 2) * 1024 + d] = v.z;
            gwT[(eb + 3) * 1024 + d] = v.w;
        }
    }
    __syncthreads();
    const int wv = tid >> 6, lane = tid & 63;
    const int t = blockIdx.x * 4 + wv;              // token for this wave
    const float* xr = x + (size_t)t * DM;
    float4 xs[4];                                   // d = i*256 + lane*4
#pragma unroll
    for (int i = 0; i < 4; ++i)
        xs[i] = *(const float4*)&xr[i * 256 + lane * 4];
    float acc[8];
#pragma unroll
    for (int e = 0; e < 8; ++e) acc[e] = 0.f;
#pragma unroll
    for (int i = 0; i < 4; ++i) {
        const int d4 = i * 256 + lane * 4;
#pragma unroll
        for (int e = 0; e < 8; ++e) {               // b128, consecutive lanes: conflict-free
            const float4 g = *(const float4*)&gwT[e * 1024 + d4];
            acc[e] += xs[i].x * g.x + xs[i].y * g.y + xs[i].z * g.z + xs[i].w * g.w;
        }
    }
    // zero out row (float4, coalesced)
    float* outr = out + (size_t)t * DM;
    const float4 z4 = make_float4(0.f, 0.f, 0.f, 0.f);
#pragma unroll
    for (int i = 0; i < 4; ++i) ((float4*)outr)[i * 64 + lane] = z4;
    // full-wave butterfly reduce: all lanes end with identical sums (uniform branches below)
#pragma unroll
    for (int off = 32; off > 0; off >>= 1) {
#pragma unroll
        for (int e = 0; e < 8; ++e) acc[e] += __shfl_xor(acc[e], off, 64);
    }
    float lg[8];
#pragma unroll
    for (int e = 0; e < 8; ++e) lg[e] = acc[e] + gb[e];
    int b1i = 0; float b1v = lg[0];
#pragma unroll
    for (int e = 1; e < 8; ++e) if (lg[e] > b1v) { b1v = lg[e]; b1i = e; }
    int b2i = -1; float b2v = -3.4e38f;
#pragma unroll
    for (int e = 0; e < 8; ++e) if (e != b1i && lg[e] > b2v) { b2v = lg[e]; b2i = e; }
    const bool sel = (b1i == 0) || (b2i == 1);
    if (sel) {      // only selected tokens are ever gathered by the GEMMs
        unsigned short* xbr = xb + (size_t)t * DM;
#pragma unroll
        for (int i = 0; i < 4; ++i) {
            uint2 pk;
            pk.x = (unsigned int)f2bf(xs[i].x) | ((unsigned int)f2bf(xs[i].y) << 16);
            pk.y = (unsigned int)f2bf(xs[i].z) | ((unsigned int)f2bf(xs[i].w) << 16);
            *(uint2*)&xbr[i * 256 + lane * 4] = pk;
        }
    }
    if (lane == 0) {
        float den = 0.f;
#pragma unroll
        for (int e = 0; e < 8; ++e) den += expf(lg[e] - b1v);
        if (b1i == 0) {                       // top-1 slot matches expert 0
            float s0 = expf(lg[0] - b1v) / den;
            int p = atomicAdd(&counts[0], 1);
            lists[p] = t; sls[p] = s0;
        }
        if (b2i == 1) {                       // top-2 slot matches expert 1
            float s1 = expf(lg[1] - b1v) / den;
            int p = atomicAdd(&counts[1], 1);
            lists[NTOK + p] = t; sls[NTOK + p] = s1;
        }
    }
    if (blockIdx.x == 0 && tid == 0) out[(size_t)NTOK * DM] = 0.0f;   // lbl == 0 exactly
}

// ---------------- kernels 2/3: MFMA GEMM, 64x64 tile, BK=64, global_load_lds dbuf ----------------
// R5: m97-style staging. global_load_lds width=16 replaces reg-staging: no staging VGPRs
// (occupancy up), no ds_writes, no vmcnt(0)-before-write stall; prefetch for tile s+1
// flies directly into LDS buf^1 during the MFMA phase of tile s; ONE barrier per step.
// LDS linear [64][64] bf16 per buffer (gll needs contiguous dest); XOR swizzle applied
// on the SOURCE chunk (qs = q ^ (row&7)) and the same XOR on frag reads (rule #21).
// Bank math: frag b128 reads land exactly 8 lanes per 4-bank slot group = 256 words /
// 32 banks = balanced minimum. LDS 32 KB -> 5 blocks/CU; VGPR ~80 -> 6 waves/SIMD.
// STAGE2=false: h = gelu(Xg @ W1 + b1) -> hout (bf16 [e][NTOK][DF])
// STAGE2=true : out[tok] += scale * (h @ W2 + b2), split-K=2, fp32 atomicAdd scatter
template <bool STAGE2>
__global__ __launch_bounds__(256, 4) void moe_gemm(const unsigned short* __restrict__ Aglob,
                                                   const unsigned short* __restrict__ Bglob,
                                                   const float* __restrict__ bias,
                                                   unsigned short* __restrict__ hout,
                                                   float* __restrict__ outp,
                                                   const int* __restrict__ counts,
                                                   const int* __restrict__ lists,
                                                   const float* __restrict__ sls) {
    constexpr int KTOT = STAGE2 ? DF : DM;
    constexpr int KS = STAGE2 ? KTOT / 2 : KTOT;   // split-K=2 on stage 2
    constexpr int NS = KS / 64;                    // 16 k-steps
    constexpr int BUF = 64 * 64;                   // one buffer, bf16 elems (8 KB)
    const int bid = blockIdx.x;
    const int g = bid & 63;
    const int m0 = (bid >> 6) * 64;
    const int n_idx = STAGE2 ? (g >> 2) : (g >> 1);
    const int e     = STAGE2 ? ((g >> 1) & 1) : (g & 1);
    const int ksp   = STAGE2 ? (g & 1) : 0;
    const int Ne = counts[e];
    if (m0 >= Ne) return;
    const int n0 = n_idx * 64;
    const int k0 = ksp * KS;
    const int tid = threadIdx.x;
    const int lane = tid & 63, wv = tid >> 6;
    const int wr = wv >> 1, wc = wv & 1;           // 2x2 wave grid; wave owns 32x32
    const int lm = lane & 15, qk = lane >> 4;

    const int* list = lists + e * NTOK;
    const unsigned short* Ae = STAGE2 ? (Aglob + (size_t)e * NTOK * DF) : Aglob;
    const unsigned short* Be = Bglob + (size_t)e * DM * DF;

    __shared__ alignas(16) unsigned short As[2 * BUF];   // 16 KB (double-buffered)
    __shared__ alignas(16) unsigned short Bs[2 * BUF];   // 16 KB

    // gll staging map: wave wv, instr j in {0,1} covers rows wv*16+j*8 .. +8 (1 KB).
    // lane: row rL = wv*16 + j*8 + (lane>>3), chunk slot q = lane&7.
    // source chunk (pre-swizzle) qs = q ^ (row&7) = q ^ (lane>>3)  [j*8, wv*16 = 0 mod 8]
    const int q  = lane & 7;
    const int qs = q ^ (lane >> 3);
    const int rL0 = wv * 16 + (lane >> 3);               // j=0 row in tile
    const int rL1 = rL0 + 8;                             // j=1 row in tile
    int rgA0 = m0 + rL0; if (rgA0 >= Ne) rgA0 = m0;      // clamp: epilogue-guarded
    int rgA1 = m0 + rL1; if (rgA1 >= Ne) rgA1 = m0;
    const size_t arow0 = STAGE2 ? (size_t)rgA0 * KTOT : (size_t)list[rgA0] * KTOT;
    const size_t arow1 = STAGE2 ? (size_t)rgA1 * KTOT : (size_t)list[rgA1] * KTOT;
    const unsigned short* sa0 = Ae + arow0 + k0 + qs * 8;
    const unsigned short* sa1 = Ae + arow1 + k0 + qs * 8;
    const unsigned short* sb0 = Be + (size_t)(n0 + rL0) * KTOT + k0 + qs * 8;
    const unsigned short* sb1 = Be + (size_t)(n0 + rL1) * KTOT + k0 + qs * 8;

    f32x4 acc00 = {0.f,0.f,0.f,0.f}, acc01 = acc00, acc10 = acc00, acc11 = acc00;

    // frag rows; (r + 16k)&7 == lm&7 -> shared swizzle key
    const int rA0 = wr * 32 + lm,      rA1 = rA0 + 16;
    const int rB0 = wc * 32 + lm,      rB1 = rB0 + 16;
    const int xsw = lm & 7;

    // prologue: tile 0 -> LDS buf 0 (direct, async)
    {
        unsigned short* a_d = &As[wv * 1024];            // wv*16 rows * 64 elems
        unsigned short* b_d = &Bs[wv * 1024];
        gll16(sa0, a_d);        gll16(sa1, a_d + 512);
        gll16(sb0, b_d);        gll16(sb1, b_d + 512);
        sa0 += 64; sa1 += 64; sb0 += 64; sb1 += 64;
    }
    __syncthreads();                                     // vmcnt(0) drained by compiler

    int cur = 0;
#pragma unroll 1
    for (int s = 0; s < NS; ++s) {
        const bool pre = (s + 1 < NS);
        if (pre) {                                   // async prefetch s+1 -> buf^1, in flight
            unsigned short* a_d = &As[(cur ^ 1) * BUF + wv * 1024];
            unsigned short* b_d = &Bs[(cur ^ 1) * BUF + wv * 1024];
            gll16(sa0, a_d);        gll16(sa1, a_d + 512);
            gll16(sb0, b_d);        gll16(sb1, b_d + 512);
            sa0 += 64; sa1 += 64; sb0 += 64; sb1 += 64;
        }
        const int rb = cur * BUF;
#pragma unroll
        for (int h = 0; h < 2; ++h) {                // two 16x16x32 k-slices of BK=64
            const int sl = ((h * 4 + qk) ^ xsw) * 8;
            s16x8 af0 = *(const s16x8*)&As[rb + rA0 * 64 + sl];
            s16x8 af1 = *(const s16x8*)&As[rb + rA1 * 64 + sl];
            s16x8 bf0 = *(const s16x8*)&Bs[rb + rB0 * 64 + sl];
            s16x8 bf1 = *(const s16x8*)&Bs[rb + rB1 * 64 + sl];
            acc00 = __builtin_amdgcn_mfma_f32_16x16x32_bf16(af0, bf0, acc00, 0, 0, 0);
            acc01 = __builtin_amdgcn_mfma_f32_16x16x32_bf16(af0, bf1, acc01, 0, 0, 0);
            acc10 = __builtin_amdgcn_mfma_f32_16x16x32_bf16(af1, bf0, acc10, 0, 0, 0);
            acc11 = __builtin_amdgcn_mfma_f32_16x16x32_bf16(af1, bf1, acc11, 0, 0, 0);
        }
        if (pre) {
            __syncthreads();                         // gll of s+1 landed; reads of s done
            cur ^= 1;
        }
    }

    // epilogue: C/D layout col = lane&15, row = (lane>>4)*4 + reg
    f32x4 accs[2][2] = {{acc00, acc01}, {acc10, acc11}};
    if (!STAGE2) {
        const float* be = bias + e * DF;
        unsigned short* he = hout + (size_t)e * NTOK * DF;
#pragma unroll
        for (int am = 0; am < 2; ++am) {
#pragma unroll
            for (int bn = 0; bn < 2; ++bn) {
                int ng = n0 + wc * 32 + bn * 16 + lm;
                float bb = be[ng];
                f32x4 v = accs[am][bn];
#pragma unroll
                for (int r = 0; r < 4; ++r) {
                    int ml = wr * 32 + am * 16 + qk * 4 + r;
                    int rg = m0 + ml;
                    if (rg < Ne) {
                        float tpre = v[r] + bb;
                        float gl = 0.5f * tpre * (1.0f + erff(tpre * 0.70710678118654752f));
                        he[(size_t)rg * DF + ng] = f2bf(gl);
                    }
                }
            }
        }
    } else {
        const float* be = bias + e * DM;
        const float* sl = sls + e * NTOK;
#pragma unroll
        for (int am = 0; am < 2; ++am) {
#pragma unroll
            for (int bn = 0; bn < 2; ++bn) {
                int ng = n0 + wc * 32 + bn * 16 + lm;
                float bb = (ksp == 0) ? be[ng] : 0.0f;       // bias added by split 0 only
                f32x4 v = accs[am][bn];
#pragma unroll
                for (int r = 0; r < 4; ++r) {
                    int ml = wr * 32 + am * 16 + qk * 4 + r;
                    int rg = m0 + ml;
                    if (rg < Ne) {
                        int tok = list[rg];
                        float s = sl[rg];
                        atomicAdd(&outp[(size_t)tok * DM + ng], s * (v[r] + bb));
                    }
                }
            }
        }
    }
}

extern "C" void kernel_launch(void* const* d_in, const int* in_sizes, int n_in,
                              void* d_out, int out_size, void* d_ws, size_t ws_size,
                              hipStream_t stream) {
    const float* x  = (const float*)d_in[0];
    const float* gw = (const float*)d_in[1];
    const float* gb = (const float*)d_in[2];
    const float* w1 = (const float*)d_in[3];
    const float* b1 = (const float*)d_in[4];
    const float* w2 = (const float*)d_in[5];
    const float* b2 = (const float*)d_in[6];
    float* out = (float*)d_out;
    char* ws = (char*)d_ws;

    // ws layout (bytes): [0] counts, [1024] lists[2][8192], [66560] sls[2][8192],
    // [262144] xb bf16[8192*1024], [+16MiB] w1t bf16[2][2048][1024],
    // [+8MiB] w2t bf16[2][1024][2048], [+8MiB] h bf16[2][8192][2048].  Total ~96.3 MB.
    int*            counts = (int*)(ws + 0);
    int*            lists  = (int*)(ws + 1024);
    float*          sls    = (float*)(ws + 1024 + 65536);
    unsigned short* xb     = (unsigned short*)(ws + 262144);
    unsigned short* w1t    = (unsigned short*)(ws + 262144 + 16777216);
    unsigned short* w2t    = (unsigned short*)(ws + 262144 + 16777216 + 8388608);
    unsigned short* hbuf   = (unsigned short*)(ws + 262144 + 16777216 + 16777216);

    hipMemsetAsync(counts, 0, 8, stream);
    wcvt_kernel<<<2048, 256, 0, stream>>>(w1, w2, w1t, w2t);
    gate_kernel<<<2048, 256, 0, stream>>>(x, gw, gb, xb, out, counts, lists, sls);
    // stage 1: bid = m*64 + (n_idx*2 + e); m-tiles up to NTOK/64 (ghosts exit on counts)
    moe_gemm<false><<<(NTOK / 64) * 64, 256, 0, stream>>>(xb, w1t, b1, hbuf, nullptr, counts, lists, sls);
    // stage 2: bid = m*64 + (n_idx*4 + e*2 + ksp), split-K=2
    moe_gemm<true><<<(NTOK / 64) * 64, 256, 0, stream>>>(hbuf, w2t, b2, nullptr, out, counts, lists, sls);
}

// Round 6
// 256.337 us; speedup vs baseline: 1.0238x; 1.0238x over previous
//
#include <hip/hip_runtime.h>
#include <hip/hip_bf16.h>
#include <stdint.h>

#define DM 1024
#define DF 2048
#define NTOK 8192

typedef float f32x4 __attribute__((ext_vector_type(4)));
typedef short s16x8 __attribute__((ext_vector_type(8)));   // 8 bf16 in 4 VGPRs

__device__ __forceinline__ unsigned short f2bf(float f) {
    union { float f; unsigned int u; } v; v.f = f;
    unsigned int r = v.u + 0x7fffu + ((v.u >> 16) & 1u);   // RNE
    return (unsigned short)(r >> 16);
}

// async global->LDS, 16B per lane (1 KB per wave-instr). Dest is wave-uniform base
// + lane*16 (HW rule); source address is per-lane (pre-swizzled there).
__device__ __forceinline__ void gll16(const unsigned short* g, unsigned short* l) {
    __builtin_amdgcn_global_load_lds(
        (const __attribute__((address_space(1))) void*)g,
        (__attribute__((address_space(3))) void*)l, 16, 0, 0);
}

// ---------------- kernel 1a: w1/w2 fp32 [k][n] -> bf16 [n][k] (experts {0,1}) ----------------
__global__ __launch_bounds__(256) void wcvt_kernel(const float* __restrict__ w1,
                                                   const float* __restrict__ w2,
                                                   unsigned short* __restrict__ w1t,
                                                   unsigned short* __restrict__ w2t) {
    __shared__ __align__(16) unsigned short tl[64 * 66];     // 8448 B
    const int b = blockIdx.x;
    const int z = b >> 9;             // 0,1: w1 e0/e1 ; 2,3: w2 e0/e1
    const int rem = b & 511;
    const int e = z & 1, is2 = z >> 1;
    const int R = is2 ? DF : DM;      // src rows (k)  == dst row stride
    const int C = is2 ? DM : DF;      // src cols (n)
    const int by = is2 ? (rem >> 4) : (rem >> 5);
    const int bx = is2 ? (rem & 15) : (rem & 31);
    const int r0 = by * 64, c0 = bx * 64;
    const float* src = is2 ? (w2 + (size_t)e * DF * DM) : (w1 + (size_t)e * DM * DF);
    unsigned short* dst = is2 ? (w2t + (size_t)e * DM * DF) : (w1t + (size_t)e * DM * DF);
    const int t = threadIdx.x;
    const int tr = t >> 4;            // 0..15
    const int tc4 = (t & 15) * 4;     // col base (float4 granularity)
#pragma unroll
    for (int i = 0; i < 4; ++i) {
        const int r = tr + 16 * i;
        const float4 v = *(const float4*)&src[(size_t)(r0 + r) * C + (c0 + tc4)];
        const unsigned int wa = (unsigned int)f2bf(v.x) | ((unsigned int)f2bf(v.y) << 16);
        const unsigned int wb = (unsigned int)f2bf(v.z) | ((unsigned int)f2bf(v.w) << 16);
        *(unsigned int*)&tl[r * 66 + tc4]     = wa;
        *(unsigned int*)&tl[r * 66 + tc4 + 2] = wb;
    }
    __syncthreads();
#pragma unroll
    for (int i = 0; i < 2; ++i) {
        const int p = t + 256 * i;    // 512 output uint4 per tile
        const int cp = p >> 3;        // dst row (= src col), 0..63
        const int rc = p & 7;         // dst 8-col chunk (= src row block)
        unsigned int wds[4];
#pragma unroll
        for (int j = 0; j < 4; ++j) {
            const unsigned short a  = tl[(8 * rc + 2 * j)     * 66 + cp];
            const unsigned short bb = tl[(8 * rc + 2 * j + 1) * 66 + cp];
            wds[j] = (unsigned int)a | ((unsigned int)bb << 16);
        }
        *(uint4*)&dst[(size_t)(c0 + cp) * R + (r0 + 8 * rc)] = *(const uint4*)wds;
    }
}

// ---------------- kernel 1b: gating + zero-out + selective x->bf16 ----------------
__global__ __launch_bounds__(256) void gate_kernel(const float* __restrict__ x,
                                                   const float* __restrict__ gw,
                                                   const float* __restrict__ gb,
                                                   unsigned short* __restrict__ xb,
                                                   float* __restrict__ out,
                                                   int* __restrict__ counts,
                                                   int* __restrict__ lists,
                                                   float* __restrict__ sls) {
    __shared__ float gwT[8192];                     // gwT[e*1024 + d], 32 KB
    const int tid = threadIdx.x;
    {   // gw [1024][8] fp32 -> gwT[e][d]; coalesced float4 loads, 2-way-free scatter
        const float4* g4 = (const float4*)gw;       // 2048 float4
#pragma unroll
        for (int i = 0; i < 8; ++i) {
            const int q = tid + 256 * i;
            const float4 v = g4[q];
            const int d = q >> 1, eb = 4 * (q & 1);
            gwT[(eb + 0) * 1024 + d] = v.x;
            gwT[(eb + 1) * 1024 + d] = v.y;
            gwT[(eb + 2) * 1024 + d] = v.z;
            gwT[(eb + 3) * 1024 + d] = v.w;
        }
    }
    __syncthreads();
    const int wv = tid >> 6, lane = tid & 63;
    const int t = blockIdx.x * 4 + wv;              // token for this wave
    const float* xr = x + (size_t)t * DM;
    float4 xs[4];                                   // d = i*256 + lane*4
#pragma unroll
    for (int i = 0; i < 4; ++i)
        xs[i] = *(const float4*)&xr[i * 256 + lane * 4];
    float acc[8];
#pragma unroll
    for (int e = 0; e < 8; ++e) acc[e] = 0.f;
#pragma unroll
    for (int i = 0; i < 4; ++i) {
        const int d4 = i * 256 + lane * 4;
#pragma unroll
        for (int e = 0; e < 8; ++e) {               // b128, consecutive lanes: conflict-free
            const float4 g = *(const float4*)&gwT[e * 1024 + d4];
            acc[e] += xs[i].x * g.x + xs[i].y * g.y + xs[i].z * g.z + xs[i].w * g.w;
        }
    }
    // zero out row (float4, coalesced)
    float* outr = out + (size_t)t * DM;
    const float4 z4 = make_float4(0.f, 0.f, 0.f, 0.f);
#pragma unroll
    for (int i = 0; i < 4; ++i) ((float4*)outr)[i * 64 + lane] = z4;
    // full-wave butterfly reduce: all lanes end with identical sums (uniform branches below)
#pragma unroll
    for (int off = 32; off > 0; off >>= 1) {
#pragma unroll
        for (int e = 0; e < 8; ++e) acc[e] += __shfl_xor(acc[e], off, 64);
    }
    float lg[8];
#pragma unroll
    for (int e = 0; e < 8; ++e) lg[e] = acc[e] + gb[e];
    int b1i = 0; float b1v = lg[0];
#pragma unroll
    for (int e = 1; e < 8; ++e) if (lg[e] > b1v) { b1v = lg[e]; b1i = e; }
    int b2i = -1; float b2v = -3.4e38f;
#pragma unroll
    for (int e = 0; e < 8; ++e) if (e != b1i && lg[e] > b2v) { b2v = lg[e]; b2i = e; }
    const bool sel = (b1i == 0) || (b2i == 1);
    if (sel) {      // only selected tokens are ever gathered by the GEMMs
        unsigned short* xbr = xb + (size_t)t * DM;
#pragma unroll
        for (int i = 0; i < 4; ++i) {
            uint2 pk;
            pk.x = (unsigned int)f2bf(xs[i].x) | ((unsigned int)f2bf(xs[i].y) << 16);
            pk.y = (unsigned int)f2bf(xs[i].z) | ((unsigned int)f2bf(xs[i].w) << 16);
            *(uint2*)&xbr[i * 256 + lane * 4] = pk;
        }
    }
    if (lane == 0) {
        float den = 0.f;
#pragma unroll
        for (int e = 0; e < 8; ++e) den += expf(lg[e] - b1v);
        if (b1i == 0) {                       // top-1 slot matches expert 0
            float s0 = expf(lg[0] - b1v) / den;
            int p = atomicAdd(&counts[0], 1);
            lists[p] = t; sls[p] = s0;
        }
        if (b2i == 1) {                       // top-2 slot matches expert 1
            float s1 = expf(lg[1] - b1v) / den;
            int p = atomicAdd(&counts[1], 1);
            lists[NTOK + p] = t; sls[NTOK + p] = s1;
        }
    }
    if (blockIdx.x == 0 && tid == 0) out[(size_t)NTOK * DM] = 0.0f;   // lbl == 0 exactly
}

// ---------------- kernels 2/3: MFMA GEMM, 64x64 tile, BK=64, gll + counted-vmcnt pipeline ----------------
// R6: T4 counted vmcnt. R5's __syncthreads drained vmcnt(0) -> every step waited for the
// JUST-ISSUED prefetch (full L2 latency serially, 16x). Now: triple LDS buffer, 2-deep
// prefetch; per step: s_waitcnt vmcnt(4) (tile s landed; tile s+1's 4 gll stay in flight)
// -> raw s_barrier (each wave drained own counter before barrier => all waves' tile-s
// loads visible) -> sched_barrier -> issue tile s+2 -> MFMA tile s.
// Race audit: issue(s+2) overwrites buf[(s-1)%3]; all waves finished compute(s-1) before
// this step's barrier. Final step waits vmcnt(0). Tile-s loads get ~2 compute phases of
// head start -> barrier stall ~0. LDS 48 KB -> 3 blocks/CU; VGPR ~44.
// STAGE2=false: h = gelu(Xg @ W1 + b1) -> hout (bf16 [e][NTOK][DF])
// STAGE2=true : out[tok] += scale * (h @ W2 + b2), split-K=2, fp32 atomicAdd scatter
template <bool STAGE2>
__global__ __launch_bounds__(256) void moe_gemm(const unsigned short* __restrict__ Aglob,
                                                const unsigned short* __restrict__ Bglob,
                                                const float* __restrict__ bias,
                                                unsigned short* __restrict__ hout,
                                                float* __restrict__ outp,
                                                const int* __restrict__ counts,
                                                const int* __restrict__ lists,
                                                const float* __restrict__ sls) {
    constexpr int KTOT = STAGE2 ? DF : DM;
    constexpr int KS = STAGE2 ? KTOT / 2 : KTOT;   // split-K=2 on stage 2
    constexpr int NS = KS / 64;                    // 16/8 k-steps
    constexpr int BUF = 64 * 64;                   // one buffer, bf16 elems (8 KB)
    const int bid = blockIdx.x;
    const int g = bid & 63;
    const int m0 = (bid >> 6) * 64;
    const int n_idx = STAGE2 ? (g >> 2) : (g >> 1);
    const int e     = STAGE2 ? ((g >> 1) & 1) : (g & 1);
    const int ksp   = STAGE2 ? (g & 1) : 0;
    const int Ne = counts[e];
    if (m0 >= Ne) return;
    const int n0 = n_idx * 64;
    const int k0 = ksp * KS;
    const int tid = threadIdx.x;
    const int lane = tid & 63, wv = tid >> 6;
    const int wr = wv >> 1, wc = wv & 1;           // 2x2 wave grid; wave owns 32x32
    const int lm = lane & 15, qk = lane >> 4;

    const int* list = lists + e * NTOK;
    const unsigned short* Ae = STAGE2 ? (Aglob + (size_t)e * NTOK * DF) : Aglob;
    const unsigned short* Be = Bglob + (size_t)e * DM * DF;

    __shared__ alignas(16) unsigned short As[3 * BUF];   // 24 KB (triple-buffered)
    __shared__ alignas(16) unsigned short Bs[3 * BUF];   // 24 KB

    // gll staging map: wave wv, instr j in {0,1} covers rows wv*16+j*8 .. +8 (1 KB).
    // lane: row rL = wv*16 + j*8 + (lane>>3), chunk slot q = lane&7.
    // source chunk (pre-swizzle) qs = q ^ (row&7) = q ^ (lane>>3)
    const int q  = lane & 7;
    const int qs = q ^ (lane >> 3);
    const int rL0 = wv * 16 + (lane >> 3);               // j=0 row in tile
    const int rL1 = rL0 + 8;                             // j=1 row in tile
    int rgA0 = m0 + rL0; if (rgA0 >= Ne) rgA0 = m0;      // clamp: epilogue-guarded
    int rgA1 = m0 + rL1; if (rgA1 >= Ne) rgA1 = m0;
    const size_t arow0 = STAGE2 ? (size_t)rgA0 * KTOT : (size_t)list[rgA0] * KTOT;
    const size_t arow1 = STAGE2 ? (size_t)rgA1 * KTOT : (size_t)list[rgA1] * KTOT;
    const unsigned short* sa0 = Ae + arow0 + k0 + qs * 8;
    const unsigned short* sa1 = Ae + arow1 + k0 + qs * 8;
    const unsigned short* sb0 = Be + (size_t)(n0 + rL0) * KTOT + k0 + qs * 8;
    const unsigned short* sb1 = Be + (size_t)(n0 + rL1) * KTOT + k0 + qs * 8;

    f32x4 acc00 = {0.f,0.f,0.f,0.f}, acc01 = acc00, acc10 = acc00, acc11 = acc00;

    // frag rows; (r + 16k)&7 == lm&7 -> shared swizzle key
    const int rA0 = wr * 32 + lm,      rA1 = rA0 + 16;
    const int rB0 = wc * 32 + lm,      rB1 = rB0 + 16;
    const int xsw = lm & 7;
    const int wofs = wv * 1024;                          // wave's 16-row slab in a buffer

    // prologue: issue tiles 0 and 1 (2-deep)
    {
        gll16(sa0, &As[wofs]);        gll16(sa1, &As[wofs + 512]);
        gll16(sb0, &Bs[wofs]);        gll16(sb1, &Bs[wofs + 512]);
        sa0 += 64; sa1 += 64; sb0 += 64; sb1 += 64;
        gll16(sa0, &As[BUF + wofs]);  gll16(sa1, &As[BUF + 512 + wofs]);
        gll16(sb0, &Bs[BUF + wofs]);  gll16(sb1, &Bs[BUF + 512 + wofs]);
        sa0 += 64; sa1 += 64; sb0 += 64; sb1 += 64;
    }

    int ri = 0;                                          // read buffer index
    int wi = 2;                                          // write buffer index
#pragma unroll 1
    for (int s = 0; s < NS; ++s) {
        if (s + 1 < NS) {
            asm volatile("s_waitcnt vmcnt(4)" ::: "memory");   // tile s landed (mine)
        } else {
            asm volatile("s_waitcnt vmcnt(0)" ::: "memory");   // last tile: full drain
        }
        __builtin_amdgcn_s_barrier();                    // all waves' tile-s loads visible
        __builtin_amdgcn_sched_barrier(0);               // pin: nothing hoists above
        if (s + 2 < NS) {                                // issue tile s+2 -> buf wi
            const int ab = wi * BUF + wofs;
            gll16(sa0, &As[ab]);  gll16(sa1, &As[ab + 512]);
            gll16(sb0, &Bs[ab]);  gll16(sb1, &Bs[ab + 512]);
            sa0 += 64; sa1 += 64; sb0 += 64; sb1 += 64;
        }
        const int rb = ri * BUF;
#pragma unroll
        for (int h = 0; h < 2; ++h) {                    // two 16x16x32 k-slices of BK=64
            const int sl = ((h * 4 + qk) ^ xsw) * 8;
            s16x8 af0 = *(const s16x8*)&As[rb + rA0 * 64 + sl];
            s16x8 af1 = *(const s16x8*)&As[rb + rA1 * 64 + sl];
            s16x8 bf0 = *(const s16x8*)&Bs[rb + rB0 * 64 + sl];
            s16x8 bf1 = *(const s16x8*)&Bs[rb + rB1 * 64 + sl];
            acc00 = __builtin_amdgcn_mfma_f32_16x16x32_bf16(af0, bf0, acc00, 0, 0, 0);
            acc01 = __builtin_amdgcn_mfma_f32_16x16x32_bf16(af0, bf1, acc01, 0, 0, 0);
            acc10 = __builtin_amdgcn_mfma_f32_16x16x32_bf16(af1, bf0, acc10, 0, 0, 0);
            acc11 = __builtin_amdgcn_mfma_f32_16x16x32_bf16(af1, bf1, acc11, 0, 0, 0);
        }
        ri = (ri == 2) ? 0 : ri + 1;
        wi = (wi == 2) ? 0 : wi + 1;
    }

    // epilogue: C/D layout col = lane&15, row = (lane>>4)*4 + reg
    f32x4 accs[2][2] = {{acc00, acc01}, {acc10, acc11}};
    if (!STAGE2) {
        const float* be = bias + e * DF;
        unsigned short* he = hout + (size_t)e * NTOK * DF;
#pragma unroll
        for (int am = 0; am < 2; ++am) {
#pragma unroll
            for (int bn = 0; bn < 2; ++bn) {
                int ng = n0 + wc * 32 + bn * 16 + lm;
                float bb = be[ng];
                f32x4 v = accs[am][bn];
#pragma unroll
                for (int r = 0; r < 4; ++r) {
                    int ml = wr * 32 + am * 16 + qk * 4 + r;
                    int rg = m0 + ml;
                    if (rg < Ne) {
                        float tpre = v[r] + bb;
                        float gl = 0.5f * tpre * (1.0f + erff(tpre * 0.70710678118654752f));
                        he[(size_t)rg * DF + ng] = f2bf(gl);
                    }
                }
            }
        }
    } else {
        const float* be = bias + e * DM;
        const float* sl = sls + e * NTOK;
#pragma unroll
        for (int am = 0; am < 2; ++am) {
#pragma unroll
            for (int bn = 0; bn < 2; ++bn) {
                int ng = n0 + wc * 32 + bn * 16 + lm;
                float bb = (ksp == 0) ? be[ng] : 0.0f;       // bias added by split 0 only
                f32x4 v = accs[am][bn];
#pragma unroll
                for (int r = 0; r < 4; ++r) {
                    int ml = wr * 32 + am * 16 + qk * 4 + r;
                    int rg = m0 + ml;
                    if (rg < Ne) {
                        int tok = list[rg];
                        float s = sl[rg];
                        atomicAdd(&outp[(size_t)tok * DM + ng], s * (v[r] + bb));
                    }
                }
            }
        }
    }
}

extern "C" void kernel_launch(void* const* d_in, const int* in_sizes, int n_in,
                              void* d_out, int out_size, void* d_ws, size_t ws_size,
                              hipStream_t stream) {
    const float* x  = (const float*)d_in[0];
    const float* gw = (const float*)d_in[1];
    const float* gb = (const float*)d_in[2];
    const float* w1 = (const float*)d_in[3];
    const float* b1 = (const float*)d_in[4];
    const float* w2 = (const float*)d_in[5];
    const float* b2 = (const float*)d_in[6];
    float* out = (float*)d_out;
    char* ws = (char*)d_ws;

    // ws layout (bytes): [0] counts, [1024] lists[2][8192], [66560] sls[2][8192],
    // [262144] xb bf16[8192*1024], [+16MiB] w1t bf16[2][2048][1024],
    // [+8MiB] w2t bf16[2][1024][2048], [+8MiB] h bf16[2][8192][2048].  Total ~96.3 MB.
    int*            counts = (int*)(ws + 0);
    int*            lists  = (int*)(ws + 1024);
    float*          sls    = (float*)(ws + 1024 + 65536);
    unsigned short* xb     = (unsigned short*)(ws + 262144);
    unsigned short* w1t    = (unsigned short*)(ws + 262144 + 16777216);
    unsigned short* w2t    = (unsigned short*)(ws + 262144 + 16777216 + 8388608);
    unsigned short* hbuf   = (unsigned short*)(ws + 262144 + 16777216 + 16777216);

    hipMemsetAsync(counts, 0, 8, stream);
    wcvt_kernel<<<2048, 256, 0, stream>>>(w1, w2, w1t, w2t);
    gate_kernel<<<2048, 256, 0, stream>>>(x, gw, gb, xb, out, counts, lists, sls);
    // stage 1: bid = m*64 + (n_idx*2 + e); m-tiles up to NTOK/64 (ghosts exit on counts)
    moe_gemm<false><<<(NTOK / 64) * 64, 256, 0, stream>>>(xb, w1t, b1, hbuf, nullptr, counts, lists, sls);
    // stage 2: bid = m*64 + (n_idx*4 + e*2 + ksp), split-K=2
    moe_gemm<true><<<(NTOK / 64) * 64, 256, 0, stream>>>(hbuf, w2t, b2, nullptr, out, counts, lists, sls);
}

// Round 7
// 241.126 us; speedup vs baseline: 1.0884x; 1.0631x over previous
//
#include <hip/hip_runtime.h>
#include <hip/hip_bf16.h>
#include <stdint.h>

#define DM 1024
#define DF 2048
#define NTOK 8192

typedef float f32x4 __attribute__((ext_vector_type(4)));
typedef short s16x8 __attribute__((ext_vector_type(8)));   // 8 bf16 in 4 VGPRs

__device__ __forceinline__ unsigned short f2bf(float f) {
    union { float f; unsigned int u; } v; v.f = f;
    unsigned int r = v.u + 0x7fffu + ((v.u >> 16) & 1u);   // RNE
    return (unsigned short)(r >> 16);
}

// ---------------- kernel 1: merged prep ----------------
// blocks [0,2048): w1/w2 fp32 [k][n] -> bf16 [n][k] transpose tiles.
// blocks [2048,4096): gating + zero-out + selective x->bf16 (1 token/wave).
// Merge is safe now (R1 lesson resolved): both branches are register-lean
// (~40 / ~60 VGPR), merged alloc ~64 -> no occupancy collapse. Saves one
// kernel launch + inter-launch gap vs the R2 two-kernel split.
__global__ __launch_bounds__(256) void prep_kernel(const float* __restrict__ x,
                                                   const float* __restrict__ gw,
                                                   const float* __restrict__ gb,
                                                   const float* __restrict__ w1,
                                                   const float* __restrict__ w2,
                                                   unsigned short* __restrict__ xb,
                                                   unsigned short* __restrict__ w1t,
                                                   unsigned short* __restrict__ w2t,
                                                   float* __restrict__ out,
                                                   int* __restrict__ counts,
                                                   int* __restrict__ lists,
                                                   float* __restrict__ sls) {
    __shared__ __align__(16) char smem[32768];
    const int tid = threadIdx.x;
    if (blockIdx.x < 2048) {
        // ---- weight transpose: bf16 LDS tile stride 66 (b32 writes conflict-free),
        // float4 in / uint4 out (1 KB per wave-instr) ----
        unsigned short* tl = (unsigned short*)smem;          // 64*66*2 = 8448 B
        const int b = blockIdx.x;
        const int z = b >> 9;             // 0,1: w1 e0/e1 ; 2,3: w2 e0/e1
        const int rem = b & 511;
        const int e = z & 1, is2 = z >> 1;
        const int R = is2 ? DF : DM;      // src rows (k)  == dst row stride
        const int C = is2 ? DM : DF;      // src cols (n)
        const int by = is2 ? (rem >> 4) : (rem >> 5);
        const int bx = is2 ? (rem & 15) : (rem & 31);
        const int r0 = by * 64, c0 = bx * 64;
        const float* src = is2 ? (w2 + (size_t)e * DF * DM) : (w1 + (size_t)e * DM * DF);
        unsigned short* dst = is2 ? (w2t + (size_t)e * DM * DF) : (w1t + (size_t)e * DM * DF);
        const int tr = tid >> 4;          // 0..15
        const int tc4 = (tid & 15) * 4;   // col base (float4 granularity)
#pragma unroll
        for (int i = 0; i < 4; ++i) {
            const int r = tr + 16 * i;
            const float4 v = *(const float4*)&src[(size_t)(r0 + r) * C + (c0 + tc4)];
            const unsigned int wa = (unsigned int)f2bf(v.x) | ((unsigned int)f2bf(v.y) << 16);
            const unsigned int wb = (unsigned int)f2bf(v.z) | ((unsigned int)f2bf(v.w) << 16);
            *(unsigned int*)&tl[r * 66 + tc4]     = wa;
            *(unsigned int*)&tl[r * 66 + tc4 + 2] = wb;
        }
        __syncthreads();
#pragma unroll
        for (int i = 0; i < 2; ++i) {
            const int p = tid + 256 * i;  // 512 output uint4 per tile
            const int cp = p >> 3;        // dst row (= src col), 0..63
            const int rc = p & 7;         // dst 8-col chunk (= src row block)
            unsigned int wds[4];
#pragma unroll
            for (int j = 0; j < 4; ++j) {
                const unsigned short a  = tl[(8 * rc + 2 * j)     * 66 + cp];
                const unsigned short bb = tl[(8 * rc + 2 * j + 1) * 66 + cp];
                wds[j] = (unsigned int)a | ((unsigned int)bb << 16);
            }
            *(uint4*)&dst[(size_t)(c0 + cp) * R + (r0 + 8 * rc)] = *(const uint4*)wds;
        }
        return;
    }
    // ---- gating + zero-out + selective x->bf16 : 1 token/wave (register-lean) ----
    float* gwT = (float*)smem;                      // gwT[e*1024 + d], 32 KB
    {   // gw [1024][8] fp32 -> gwT[e][d]; coalesced float4 loads, 2-way-free scatter
        const float4* g4 = (const float4*)gw;       // 2048 float4
#pragma unroll
        for (int i = 0; i < 8; ++i) {
            const int q = tid + 256 * i;
            const float4 v = g4[q];
            const int d = q >> 1, eb = 4 * (q & 1);
            gwT[(eb + 0) * 1024 + d] = v.x;
            gwT[(eb + 1) * 1024 + d] = v.y;
            gwT[(eb + 2) * 1024 + d] = v.z;
            gwT[(eb + 3) * 1024 + d] = v.w;
        }
    }
    __syncthreads();
    const int wv = tid >> 6, lane = tid & 63;
    const int t = (blockIdx.x - 2048) * 4 + wv;     // token for this wave
    const float* xr = x + (size_t)t * DM;
    float4 xs[4];                                   // d = i*256 + lane*4
#pragma unroll
    for (int i = 0; i < 4; ++i)
        xs[i] = *(const float4*)&xr[i * 256 + lane * 4];
    float acc[8];
#pragma unroll
    for (int e = 0; e < 8; ++e) acc[e] = 0.f;
#pragma unroll
    for (int i = 0; i < 4; ++i) {
        const int d4 = i * 256 + lane * 4;
#pragma unroll
        for (int e = 0; e < 8; ++e) {               // b128, consecutive lanes: conflict-free
            const float4 g = *(const float4*)&gwT[e * 1024 + d4];
            acc[e] += xs[i].x * g.x + xs[i].y * g.y + xs[i].z * g.z + xs[i].w * g.w;
        }
    }
    // zero out row (float4, coalesced)
    float* outr = out + (size_t)t * DM;
    const float4 z4 = make_float4(0.f, 0.f, 0.f, 0.f);
#pragma unroll
    for (int i = 0; i < 4; ++i) ((float4*)outr)[i * 64 + lane] = z4;
    // full-wave butterfly reduce: all lanes end with identical sums (uniform branches below)
#pragma unroll
    for (int off = 32; off > 0; off >>= 1) {
#pragma unroll
        for (int e = 0; e < 8; ++e) acc[e] += __shfl_xor(acc[e], off, 64);
    }
    float lg[8];
#pragma unroll
    for (int e = 0; e < 8; ++e) lg[e] = acc[e] + gb[e];
    int b1i = 0; float b1v = lg[0];
#pragma unroll
    for (int e = 1; e < 8; ++e) if (lg[e] > b1v) { b1v = lg[e]; b1i = e; }
    int b2i = -1; float b2v = -3.4e38f;
#pragma unroll
    for (int e = 0; e < 8; ++e) if (e != b1i && lg[e] > b2v) { b2v = lg[e]; b2i = e; }
    const bool sel = (b1i == 0) || (b2i == 1);
    if (sel) {      // only selected tokens are ever gathered by the GEMMs
        unsigned short* xbr = xb + (size_t)t * DM;
#pragma unroll
        for (int i = 0; i < 4; ++i) {
            uint2 pk;
            pk.x = (unsigned int)f2bf(xs[i].x) | ((unsigned int)f2bf(xs[i].y) << 16);
            pk.y = (unsigned int)f2bf(xs[i].z) | ((unsigned int)f2bf(xs[i].w) << 16);
            *(uint2*)&xbr[i * 256 + lane * 4] = pk;
        }
    }
    if (lane == 0) {
        float den = 0.f;
#pragma unroll
        for (int e = 0; e < 8; ++e) den += expf(lg[e] - b1v);
        if (b1i == 0) {                       // top-1 slot matches expert 0
            float s0 = expf(lg[0] - b1v) / den;
            int p = atomicAdd(&counts[0], 1);
            lists[p] = t; sls[p] = s0;
        }
        if (b2i == 1) {                       // top-2 slot matches expert 1
            float s1 = expf(lg[1] - b1v) / den;
            int p = atomicAdd(&counts[1], 1);
            lists[NTOK + p] = t; sls[NTOK + p] = s1;
        }
    }
    if (blockIdx.x == 2048 && tid == 0) out[(size_t)NTOK * DM] = 0.0f;   // lbl == 0 exactly
}

// ---------------- kernels 2/3: MFMA GEMM, 64x64 tile, BK=64, reg-prefetch double buffer ----------------
// EXACT R2 code (best measured: ~38 us/stage). R3(128^2)/R4(LDS dbuf)/R5(gll)/R6(counted
// vmcnt) all regressed or tied: this small-M GEMM is memory-service-rate bound at
// ~6.5 TB/s of L2/L3 panel traffic; residency (5 blocks/CU here) beats pipeline depth.
// LDS: row stride 80 bf16 + chunk slot q^(row&7): frag reads and writes <=2-way.
// STAGE2=false: h = gelu(Xg @ W1 + b1) -> hout (bf16 [e][NTOK][DF])
// STAGE2=true : out[tok] += scale * (h @ W2 + b2), split-K=2, fp32 atomicAdd scatter
template <bool STAGE2>
__global__ __launch_bounds__(256, 4) void moe_gemm(const unsigned short* __restrict__ Aglob,
                                                   const unsigned short* __restrict__ Bglob,
                                                   const float* __restrict__ bias,
                                                   unsigned short* __restrict__ hout,
                                                   float* __restrict__ outp,
                                                   const int* __restrict__ counts,
                                                   const int* __restrict__ lists,
                                                   const float* __restrict__ sls) {
    constexpr int KTOT = STAGE2 ? DF : DM;
    constexpr int KS = STAGE2 ? KTOT / 2 : KTOT;   // split-K=2 on stage 2
    constexpr int NS = KS / 64;                    // 16 k-steps
    constexpr int RS = 80;                         // LDS row stride in bf16
    const int bid = blockIdx.x;
    const int g = bid & 63;
    const int m0 = (bid >> 6) * 64;
    const int n_idx = STAGE2 ? (g >> 2) : (g >> 1);
    const int e     = STAGE2 ? ((g >> 1) & 1) : (g & 1);
    const int ksp   = STAGE2 ? (g & 1) : 0;
    const int Ne = counts[e];
    if (m0 >= Ne) return;
    const int n0 = n_idx * 64;
    const int k0 = ksp * KS;
    const int tid = threadIdx.x;
    const int lane = tid & 63, wv = tid >> 6;
    const int wr = wv >> 1, wc = wv & 1;           // 2x2 wave grid; wave owns 32x32
    const int lm = lane & 15, qk = lane >> 4;

    const int* list = lists + e * NTOK;
    const unsigned short* Ae = STAGE2 ? (Aglob + (size_t)e * NTOK * DF) : Aglob;
    const unsigned short* Be = Bglob + (size_t)e * DM * DF;

    __shared__ alignas(16) unsigned short As[64 * RS];   // 10 KB
    __shared__ alignas(16) unsigned short Bs[64 * RS];   // 10 KB

    // staging map: chunk c (0..511) -> row c>>3, q = c&7; LDS slot = q ^ (row&7)
    const int rowL0 = tid >> 3,          qL0 = tid & 7;
    const int rowL1 = (tid + 256) >> 3,  qL1 = tid & 7;      // (tid+256)&7 == tid&7
    const int ofs0 = rowL0 * RS + (qL0 ^ (rowL0 & 7)) * 8;
    const int ofs1 = rowL1 * RS + (qL1 ^ (rowL1 & 7)) * 8;
    int rgA0 = m0 + rowL0; if (rgA0 >= Ne) rgA0 = m0;        // clamp: epilogue-guarded
    int rgA1 = m0 + rowL1; if (rgA1 >= Ne) rgA1 = m0;
    const size_t arow0 = STAGE2 ? (size_t)rgA0 * KTOT : (size_t)list[rgA0] * KTOT;
    const size_t arow1 = STAGE2 ? (size_t)rgA1 * KTOT : (size_t)list[rgA1] * KTOT;
    const unsigned short* sa0 = Ae + arow0 + k0 + qL0 * 8;
    const unsigned short* sa1 = Ae + arow1 + k0 + qL1 * 8;
    const unsigned short* sb0 = Be + (size_t)(n0 + rowL0) * KTOT + k0 + qL0 * 8;
    const unsigned short* sb1 = Be + (size_t)(n0 + rowL1) * KTOT + k0 + qL1 * 8;

    f32x4 acc00 = {0.f,0.f,0.f,0.f}, acc01 = acc00, acc10 = acc00, acc11 = acc00;

    // frag read offsets (bf16 elems): row rA*RS + (chunk ^ (rA&7))*8, chunk = h*4+qk
    const int rA0 = wr * 32 + lm,      rA1 = rA0 + 16;
    const int rB0 = wc * 32 + lm,      rB1 = rB0 + 16;

    // prologue: tile 0 -> regs -> LDS
    uint4 pa0 = *(const uint4*)sa0; sa0 += 64;
    uint4 pa1 = *(const uint4*)sa1; sa1 += 64;
    uint4 pb0 = *(const uint4*)sb0; sb0 += 64;
    uint4 pb1 = *(const uint4*)sb1; sb1 += 64;
    *(uint4*)&As[ofs0] = pa0;  *(uint4*)&As[ofs1] = pa1;
    *(uint4*)&Bs[ofs0] = pb0;  *(uint4*)&Bs[ofs1] = pb1;
    __syncthreads();

#pragma unroll 1
    for (int s = 0; s < NS; ++s) {
        const bool pre = (s + 1 < NS);
        if (pre) {                                   // prefetch tile s+1 (in flight during MFMA)
            pa0 = *(const uint4*)sa0; sa0 += 64;
            pa1 = *(const uint4*)sa1; sa1 += 64;
            pb0 = *(const uint4*)sb0; sb0 += 64;
            pb1 = *(const uint4*)sb1; sb1 += 64;
        }
#pragma unroll
        for (int h = 0; h < 2; ++h) {                // two 16x16x32 k-slices of BK=64
            const int c = h * 4 + qk;
            s16x8 af0 = *(const s16x8*)&As[rA0 * RS + ((c ^ (rA0 & 7)) * 8)];
            s16x8 af1 = *(const s16x8*)&As[rA1 * RS + ((c ^ (rA1 & 7)) * 8)];
            s16x8 bf0 = *(const s16x8*)&Bs[rB0 * RS + ((c ^ (rB0 & 7)) * 8)];
            s16x8 bf1 = *(const s16x8*)&Bs[rB1 * RS + ((c ^ (rB1 & 7)) * 8)];
            acc00 = __builtin_amdgcn_mfma_f32_16x16x32_bf16(af0, bf0, acc00, 0, 0, 0);
            acc01 = __builtin_amdgcn_mfma_f32_16x16x32_bf16(af0, bf1, acc01, 0, 0, 0);
            acc10 = __builtin_amdgcn_mfma_f32_16x16x32_bf16(af1, bf0, acc10, 0, 0, 0);
            acc11 = __builtin_amdgcn_mfma_f32_16x16x32_bf16(af1, bf1, acc11, 0, 0, 0);
        }
        if (pre) {
            __syncthreads();                         // all waves done reading LDS
            *(uint4*)&As[ofs0] = pa0;  *(uint4*)&As[ofs1] = pa1;
            *(uint4*)&Bs[ofs0] = pb0;  *(uint4*)&Bs[ofs1] = pb1;
            __syncthreads();                         // staging visible
        }
    }

    // epilogue: C/D layout col = lane&15, row = (lane>>4)*4 + reg
    f32x4 accs[2][2] = {{acc00, acc01}, {acc10, acc11}};
    if (!STAGE2) {
        const float* be = bias + e * DF;
        unsigned short* he = hout + (size_t)e * NTOK * DF;
#pragma unroll
        for (int am = 0; am < 2; ++am) {
#pragma unroll
            for (int bn = 0; bn < 2; ++bn) {
                int ng = n0 + wc * 32 + bn * 16 + lm;
                float bb = be[ng];
                f32x4 v = accs[am][bn];
#pragma unroll
                for (int r = 0; r < 4; ++r) {
                    int ml = wr * 32 + am * 16 + qk * 4 + r;
                    int rg = m0 + ml;
                    if (rg < Ne) {
                        float tpre = v[r] + bb;
                        float gl = 0.5f * tpre * (1.0f + erff(tpre * 0.70710678118654752f));
                        he[(size_t)rg * DF + ng] = f2bf(gl);
                    }
                }
            }
        }
    } else {
        const float* be = bias + e * DM;
        const float* sl = sls + e * NTOK;
#pragma unroll
        for (int am = 0; am < 2; ++am) {
#pragma unroll
            for (int bn = 0; bn < 2; ++bn) {
                int ng = n0 + wc * 32 + bn * 16 + lm;
                float bb = (ksp == 0) ? be[ng] : 0.0f;       // bias added by split 0 only
                f32x4 v = accs[am][bn];
#pragma unroll
                for (int r = 0; r < 4; ++r) {
                    int ml = wr * 32 + am * 16 + qk * 4 + r;
                    int rg = m0 + ml;
                    if (rg < Ne) {
                        int tok = list[rg];
                        float s = sl[rg];
                        atomicAdd(&outp[(size_t)tok * DM + ng], s * (v[r] + bb));
                    }
                }
            }
        }
    }
}

extern "C" void kernel_launch(void* const* d_in, const int* in_sizes, int n_in,
                              void* d_out, int out_size, void* d_ws, size_t ws_size,
                              hipStream_t stream) {
    const float* x  = (const float*)d_in[0];
    const float* gw = (const float*)d_in[1];
    const float* gb = (const float*)d_in[2];
    const float* w1 = (const float*)d_in[3];
    const float* b1 = (const float*)d_in[4];
    const float* w2 = (const float*)d_in[5];
    const float* b2 = (const float*)d_in[6];
    float* out = (float*)d_out;
    char* ws = (char*)d_ws;

    // ws layout (bytes): [0] counts, [1024] lists[2][8192], [66560] sls[2][8192],
    // [262144] xb bf16[8192*1024], [+16MiB] w1t bf16[2][2048][1024],
    // [+8MiB] w2t bf16[2][1024][2048], [+8MiB] h bf16[2][8192][2048].  Total ~96.3 MB.
    int*            counts = (int*)(ws + 0);
    int*            lists  = (int*)(ws + 1024);
    float*          sls    = (float*)(ws + 1024 + 65536);
    unsigned short* xb     = (unsigned short*)(ws + 262144);
    unsigned short* w1t    = (unsigned short*)(ws + 262144 + 16777216);
    unsigned short* w2t    = (unsigned short*)(ws + 262144 + 16777216 + 8388608);
    unsigned short* hbuf   = (unsigned short*)(ws + 262144 + 16777216 + 16777216);

    hipMemsetAsync(counts, 0, 8, stream);
    // blocks [0,2048): transpose tiles; [2048,4096): gating (4 tokens/block)
    prep_kernel<<<4096, 256, 0, stream>>>(x, gw, gb, w1, w2, xb, w1t, w2t,
                                          out, counts, lists, sls);
    // stage 1: bid = m*64 + (n_idx*2 + e); m-tiles up to NTOK/64 (ghosts exit on counts)
    moe_gemm<false><<<(NTOK / 64) * 64, 256, 0, stream>>>(xb, w1t, b1, hbuf, nullptr, counts, lists, sls);
    // stage 2: bid = m*64 + (n_idx*4 + e*2 + ksp), split-K=2
    moe_gemm<true><<<(NTOK / 64) * 64, 256, 0, stream>>>(hbuf, w2t, b2, nullptr, out, counts, lists, sls);
}

// Round 8
// 238.225 us; speedup vs baseline: 1.1017x; 1.0122x over previous
//
#include <hip/hip_runtime.h>
#include <hip/hip_bf16.h>
#include <stdint.h>

#define DM 1024
#define DF 2048
#define NTOK 8192

typedef float f32x4 __attribute__((ext_vector_type(4)));
typedef short s16x8 __attribute__((ext_vector_type(8)));   // 8 bf16 in 4 VGPRs

__device__ __forceinline__ unsigned short f2bf(float f) {
    union { float f; unsigned int u; } v; v.f = f;
    unsigned int r = v.u + 0x7fffu + ((v.u >> 16) & 1u);   // RNE
    return (unsigned short)(r >> 16);
}

// ---------------- kernel 1: merged prep ----------------
// blocks [0,2048): w1/w2 fp32 [k][n] -> bf16 [n][k] transpose tiles.
// blocks [2048,4096): gating + zero-out + selective x->bf16 (1 token/wave).
// (R7: merged beats split by ~2 us — one less launch gap; both branches register-lean.)
__global__ __launch_bounds__(256) void prep_kernel(const float* __restrict__ x,
                                                   const float* __restrict__ gw,
                                                   const float* __restrict__ gb,
                                                   const float* __restrict__ w1,
                                                   const float* __restrict__ w2,
                                                   unsigned short* __restrict__ xb,
                                                   unsigned short* __restrict__ w1t,
                                                   unsigned short* __restrict__ w2t,
                                                   float* __restrict__ out,
                                                   int* __restrict__ counts,
                                                   int* __restrict__ lists,
                                                   float* __restrict__ sls) {
    __shared__ __align__(16) char smem[32768];
    const int tid = threadIdx.x;
    if (blockIdx.x < 2048) {
        // ---- weight transpose: bf16 LDS tile stride 66 (b32 writes conflict-free),
        // float4 in / uint4 out (1 KB per wave-instr) ----
        unsigned short* tl = (unsigned short*)smem;          // 64*66*2 = 8448 B
        const int b = blockIdx.x;
        const int z = b >> 9;             // 0,1: w1 e0/e1 ; 2,3: w2 e0/e1
        const int rem = b & 511;
        const int e = z & 1, is2 = z >> 1;
        const int R = is2 ? DF : DM;      // src rows (k)  == dst row stride
        const int C = is2 ? DM : DF;      // src cols (n)
        const int by = is2 ? (rem >> 4) : (rem >> 5);
        const int bx = is2 ? (rem & 15) : (rem & 31);
        const int r0 = by * 64, c0 = bx * 64;
        const float* src = is2 ? (w2 + (size_t)e * DF * DM) : (w1 + (size_t)e * DM * DF);
        unsigned short* dst = is2 ? (w2t + (size_t)e * DM * DF) : (w1t + (size_t)e * DM * DF);
        const int tr = tid >> 4;          // 0..15
        const int tc4 = (tid & 15) * 4;   // col base (float4 granularity)
#pragma unroll
        for (int i = 0; i < 4; ++i) {
            const int r = tr + 16 * i;
            const float4 v = *(const float4*)&src[(size_t)(r0 + r) * C + (c0 + tc4)];
            const unsigned int wa = (unsigned int)f2bf(v.x) | ((unsigned int)f2bf(v.y) << 16);
            const unsigned int wb = (unsigned int)f2bf(v.z) | ((unsigned int)f2bf(v.w) << 16);
            *(unsigned int*)&tl[r * 66 + tc4]     = wa;
            *(unsigned int*)&tl[r * 66 + tc4 + 2] = wb;
        }
        __syncthreads();
#pragma unroll
        for (int i = 0; i < 2; ++i) {
            const int p = tid + 256 * i;  // 512 output uint4 per tile
            const int cp = p >> 3;        // dst row (= src col), 0..63
            const int rc = p & 7;         // dst 8-col chunk (= src row block)
            unsigned int wds[4];
#pragma unroll
            for (int j = 0; j < 4; ++j) {
                const unsigned short a  = tl[(8 * rc + 2 * j)     * 66 + cp];
                const unsigned short bb = tl[(8 * rc + 2 * j + 1) * 66 + cp];
                wds[j] = (unsigned int)a | ((unsigned int)bb << 16);
            }
            *(uint4*)&dst[(size_t)(c0 + cp) * R + (r0 + 8 * rc)] = *(const uint4*)wds;
        }
        return;
    }
    // ---- gating + zero-out + selective x->bf16 : 1 token/wave (register-lean) ----
    float* gwT = (float*)smem;                      // gwT[e*1024 + d], 32 KB
    {   // gw [1024][8] fp32 -> gwT[e][d]; coalesced float4 loads, 2-way-free scatter
        const float4* g4 = (const float4*)gw;       // 2048 float4
#pragma unroll
        for (int i = 0; i < 8; ++i) {
            const int q = tid + 256 * i;
            const float4 v = g4[q];
            const int d = q >> 1, eb = 4 * (q & 1);
            gwT[(eb + 0) * 1024 + d] = v.x;
            gwT[(eb + 1) * 1024 + d] = v.y;
            gwT[(eb + 2) * 1024 + d] = v.z;
            gwT[(eb + 3) * 1024 + d] = v.w;
        }
    }
    __syncthreads();
    const int wv = tid >> 6, lane = tid & 63;
    const int t = (blockIdx.x - 2048) * 4 + wv;     // token for this wave
    const float* xr = x + (size_t)t * DM;
    float4 xs[4];                                   // d = i*256 + lane*4
#pragma unroll
    for (int i = 0; i < 4; ++i)
        xs[i] = *(const float4*)&xr[i * 256 + lane * 4];
    float acc[8];
#pragma unroll
    for (int e = 0; e < 8; ++e) acc[e] = 0.f;
#pragma unroll
    for (int i = 0; i < 4; ++i) {
        const int d4 = i * 256 + lane * 4;
#pragma unroll
        for (int e = 0; e < 8; ++e) {               // b128, consecutive lanes: conflict-free
            const float4 g = *(const float4*)&gwT[e * 1024 + d4];
            acc[e] += xs[i].x * g.x + xs[i].y * g.y + xs[i].z * g.z + xs[i].w * g.w;
        }
    }
    // zero out row (float4, coalesced)
    float* outr = out + (size_t)t * DM;
    const float4 z4 = make_float4(0.f, 0.f, 0.f, 0.f);
#pragma unroll
    for (int i = 0; i < 4; ++i) ((float4*)outr)[i * 64 + lane] = z4;
    // full-wave butterfly reduce: all lanes end with identical sums (uniform branches below)
#pragma unroll
    for (int off = 32; off > 0; off >>= 1) {
#pragma unroll
        for (int e = 0; e < 8; ++e) acc[e] += __shfl_xor(acc[e], off, 64);
    }
    float lg[8];
#pragma unroll
    for (int e = 0; e < 8; ++e) lg[e] = acc[e] + gb[e];
    int b1i = 0; float b1v = lg[0];
#pragma unroll
    for (int e = 1; e < 8; ++e) if (lg[e] > b1v) { b1v = lg[e]; b1i = e; }
    int b2i = -1; float b2v = -3.4e38f;
#pragma unroll
    for (int e = 0; e < 8; ++e) if (e != b1i && lg[e] > b2v) { b2v = lg[e]; b2i = e; }
    const bool sel = (b1i == 0) || (b2i == 1);
    if (sel) {      // only selected tokens are ever gathered by the GEMMs
        unsigned short* xbr = xb + (size_t)t * DM;
#pragma unroll
        for (int i = 0; i < 4; ++i) {
            uint2 pk;
            pk.x = (unsigned int)f2bf(xs[i].x) | ((unsigned int)f2bf(xs[i].y) << 16);
            pk.y = (unsigned int)f2bf(xs[i].z) | ((unsigned int)f2bf(xs[i].w) << 16);
            *(uint2*)&xbr[i * 256 + lane * 4] = pk;
        }
    }
    if (lane == 0) {
        float den = 0.f;
#pragma unroll
        for (int e = 0; e < 8; ++e) den += expf(lg[e] - b1v);
        if (b1i == 0) {                       // top-1 slot matches expert 0
            float s0 = expf(lg[0] - b1v) / den;
            int p = atomicAdd(&counts[0], 1);
            lists[p] = t; sls[p] = s0;
        }
        if (b2i == 1) {                       // top-2 slot matches expert 1
            float s1 = expf(lg[1] - b1v) / den;
            int p = atomicAdd(&counts[1], 1);
            lists[NTOK + p] = t; sls[NTOK + p] = s1;
        }
    }
    if (blockIdx.x == 2048 && tid == 0) out[(size_t)NTOK * DM] = 0.0f;   // lbl == 0 exactly
}

// ---------------- kernels 2/3: MFMA GEMM, 64x64 tile, BK=64, reg-prefetch double buffer ----------------
// R2 code (best measured: ~38 us/stage) + R8: XCD-locality bid swizzle.
// Old decode bid=m*64+g: same-A blocks (g consecutive) round-robin over all 8 XCDs (A-tile
// fetched into 8 L2s); same-B blocks are 64 apart (same XCD) but 63 tiles apart in time
// (8MB working set > 4MB L2 -> evicted). New decode: gchunk=bid&7 pins 8 g's per XCD
// (assuming round-robin dispatch XCD ~ bid%8); per-XCD working set = 8 B-tiles (1MB) +
// all A-tiles (~2.3MB) fits the private 4MB L2 -> panel traffic served from L2 not L3.
// Pure index remap: same work, same code; if dispatch isn't round-robin it only costs locality.
// STAGE2=false: h = gelu(Xg @ W1 + b1) -> hout (bf16 [e][NTOK][DF])
// STAGE2=true : out[tok] += scale * (h @ W2 + b2), split-K=2, fp32 atomicAdd scatter
template <bool STAGE2>
__global__ __launch_bounds__(256, 4) void moe_gemm(const unsigned short* __restrict__ Aglob,
                                                   const unsigned short* __restrict__ Bglob,
                                                   const float* __restrict__ bias,
                                                   unsigned short* __restrict__ hout,
                                                   float* __restrict__ outp,
                                                   const int* __restrict__ counts,
                                                   const int* __restrict__ lists,
                                                   const float* __restrict__ sls) {
    constexpr int KTOT = STAGE2 ? DF : DM;
    constexpr int KS = STAGE2 ? KTOT / 2 : KTOT;   // split-K=2 on stage 2
    constexpr int NS = KS / 64;                    // 16 k-steps
    constexpr int RS = 80;                         // LDS row stride in bf16
    const int bid = blockIdx.x;
    // XCD-locality swizzle: bid = m*64 + gin*8 + gchunk  ->  work (m, g = gchunk*8+gin)
    const int gch = bid & 7;
    const int gin = (bid >> 3) & 7;
    const int g = gch * 8 + gin;
    const int m0 = (bid >> 6) * 64;
    const int n_idx = STAGE2 ? (g >> 2) : (g >> 1);
    const int e     = STAGE2 ? ((g >> 1) & 1) : (g & 1);
    const int ksp   = STAGE2 ? (g & 1) : 0;
    const int Ne = counts[e];
    if (m0 >= Ne) return;
    const int n0 = n_idx * 64;
    const int k0 = ksp * KS;
    const int tid = threadIdx.x;
    const int lane = tid & 63, wv = tid >> 6;
    const int wr = wv >> 1, wc = wv & 1;           // 2x2 wave grid; wave owns 32x32
    const int lm = lane & 15, qk = lane >> 4;

    const int* list = lists + e * NTOK;
    const unsigned short* Ae = STAGE2 ? (Aglob + (size_t)e * NTOK * DF) : Aglob;
    const unsigned short* Be = Bglob + (size_t)e * DM * DF;

    __shared__ alignas(16) unsigned short As[64 * RS];   // 10 KB
    __shared__ alignas(16) unsigned short Bs[64 * RS];   // 10 KB

    // staging map: chunk c (0..511) -> row c>>3, q = c&7; LDS slot = q ^ (row&7)
    const int rowL0 = tid >> 3,          qL0 = tid & 7;
    const int rowL1 = (tid + 256) >> 3,  qL1 = tid & 7;      // (tid+256)&7 == tid&7
    const int ofs0 = rowL0 * RS + (qL0 ^ (rowL0 & 7)) * 8;
    const int ofs1 = rowL1 * RS + (qL1 ^ (rowL1 & 7)) * 8;
    int rgA0 = m0 + rowL0; if (rgA0 >= Ne) rgA0 = m0;        // clamp: epilogue-guarded
    int rgA1 = m0 + rowL1; if (rgA1 >= Ne) rgA1 = m0;
    const size_t arow0 = STAGE2 ? (size_t)rgA0 * KTOT : (size_t)list[rgA0] * KTOT;
    const size_t arow1 = STAGE2 ? (size_t)rgA1 * KTOT : (size_t)list[rgA1] * KTOT;
    const unsigned short* sa0 = Ae + arow0 + k0 + qL0 * 8;
    const unsigned short* sa1 = Ae + arow1 + k0 + qL1 * 8;
    const unsigned short* sb0 = Be + (size_t)(n0 + rowL0) * KTOT + k0 + qL0 * 8;
    const unsigned short* sb1 = Be + (size_t)(n0 + rowL1) * KTOT + k0 + qL1 * 8;

    f32x4 acc00 = {0.f,0.f,0.f,0.f}, acc01 = acc00, acc10 = acc00, acc11 = acc00;

    // frag read offsets (bf16 elems): row rA*RS + (chunk ^ (rA&7))*8, chunk = h*4+qk
    const int rA0 = wr * 32 + lm,      rA1 = rA0 + 16;
    const int rB0 = wc * 32 + lm,      rB1 = rB0 + 16;

    // prologue: tile 0 -> regs -> LDS
    uint4 pa0 = *(const uint4*)sa0; sa0 += 64;
    uint4 pa1 = *(const uint4*)sa1; sa1 += 64;
    uint4 pb0 = *(const uint4*)sb0; sb0 += 64;
    uint4 pb1 = *(const uint4*)sb1; sb1 += 64;
    *(uint4*)&As[ofs0] = pa0;  *(uint4*)&As[ofs1] = pa1;
    *(uint4*)&Bs[ofs0] = pb0;  *(uint4*)&Bs[ofs1] = pb1;
    __syncthreads();

#pragma unroll 1
    for (int s = 0; s < NS; ++s) {
        const bool pre = (s + 1 < NS);
        if (pre) {                                   // prefetch tile s+1 (in flight during MFMA)
            pa0 = *(const uint4*)sa0; sa0 += 64;
            pa1 = *(const uint4*)sa1; sa1 += 64;
            pb0 = *(const uint4*)sb0; sb0 += 64;
            pb1 = *(const uint4*)sb1; sb1 += 64;
        }
#pragma unroll
        for (int h = 0; h < 2; ++h) {                // two 16x16x32 k-slices of BK=64
            const int c = h * 4 + qk;
            s16x8 af0 = *(const s16x8*)&As[rA0 * RS + ((c ^ (rA0 & 7)) * 8)];
            s16x8 af1 = *(const s16x8*)&As[rA1 * RS + ((c ^ (rA1 & 7)) * 8)];
            s16x8 bf0 = *(const s16x8*)&Bs[rB0 * RS + ((c ^ (rB0 & 7)) * 8)];
            s16x8 bf1 = *(const s16x8*)&Bs[rB1 * RS + ((c ^ (rB1 & 7)) * 8)];
            acc00 = __builtin_amdgcn_mfma_f32_16x16x32_bf16(af0, bf0, acc00, 0, 0, 0);
            acc01 = __builtin_amdgcn_mfma_f32_16x16x32_bf16(af0, bf1, acc01, 0, 0, 0);
            acc10 = __builtin_amdgcn_mfma_f32_16x16x32_bf16(af1, bf0, acc10, 0, 0, 0);
            acc11 = __builtin_amdgcn_mfma_f32_16x16x32_bf16(af1, bf1, acc11, 0, 0, 0);
        }
        if (pre) {
            __syncthreads();                         // all waves done reading LDS
            *(uint4*)&As[ofs0] = pa0;  *(uint4*)&As[ofs1] = pa1;
            *(uint4*)&Bs[ofs0] = pb0;  *(uint4*)&Bs[ofs1] = pb1;
            __syncthreads();                         // staging visible
        }
    }

    // epilogue: C/D layout col = lane&15, row = (lane>>4)*4 + reg
    f32x4 accs[2][2] = {{acc00, acc01}, {acc10, acc11}};
    if (!STAGE2) {
        const float* be = bias + e * DF;
        unsigned short* he = hout + (size_t)e * NTOK * DF;
#pragma unroll
        for (int am = 0; am < 2; ++am) {
#pragma unroll
            for (int bn = 0; bn < 2; ++bn) {
                int ng = n0 + wc * 32 + bn * 16 + lm;
                float bb = be[ng];
                f32x4 v = accs[am][bn];
#pragma unroll
                for (int r = 0; r < 4; ++r) {
                    int ml = wr * 32 + am * 16 + qk * 4 + r;
                    int rg = m0 + ml;
                    if (rg < Ne) {
                        float tpre = v[r] + bb;
                        float gl = 0.5f * tpre * (1.0f + erff(tpre * 0.70710678118654752f));
                        he[(size_t)rg * DF + ng] = f2bf(gl);
                    }
                }
            }
        }
    } else {
        const float* be = bias + e * DM;
        const float* sl = sls + e * NTOK;
#pragma unroll
        for (int am = 0; am < 2; ++am) {
#pragma unroll
            for (int bn = 0; bn < 2; ++bn) {
                int ng = n0 + wc * 32 + bn * 16 + lm;
                float bb = (ksp == 0) ? be[ng] : 0.0f;       // bias added by split 0 only
                f32x4 v = accs[am][bn];
#pragma unroll
                for (int r = 0; r < 4; ++r) {
                    int ml = wr * 32 + am * 16 + qk * 4 + r;
                    int rg = m0 + ml;
                    if (rg < Ne) {
                        int tok = list[rg];
                        float s = sl[rg];
                        atomicAdd(&outp[(size_t)tok * DM + ng], s * (v[r] + bb));
                    }
                }
            }
        }
    }
}

extern "C" void kernel_launch(void* const* d_in, const int* in_sizes, int n_in,
                              void* d_out, int out_size, void* d_ws, size_t ws_size,
                              hipStream_t stream) {
    const float* x  = (const float*)d_in[0];
    const float* gw = (const float*)d_in[1];
    const float* gb = (const float*)d_in[2];
    const float* w1 = (const float*)d_in[3];
    const float* b1 = (const float*)d_in[4];
    const float* w2 = (const float*)d_in[5];
    const float* b2 = (const float*)d_in[6];
    float* out = (float*)d_out;
    char* ws = (char*)d_ws;

    // ws layout (bytes): [0] counts, [1024] lists[2][8192], [66560] sls[2][8192],
    // [262144] xb bf16[8192*1024], [+16MiB] w1t bf16[2][2048][1024],
    // [+8MiB] w2t bf16[2][1024][2048], [+8MiB] h bf16[2][8192][2048].  Total ~96.3 MB.
    int*            counts = (int*)(ws + 0);
    int*            lists  = (int*)(ws + 1024);
    float*          sls    = (float*)(ws + 1024 + 65536);
    unsigned short* xb     = (unsigned short*)(ws + 262144);
    unsigned short* w1t    = (unsigned short*)(ws + 262144 + 16777216);
    unsigned short* w2t    = (unsigned short*)(ws + 262144 + 16777216 + 8388608);
    unsigned short* hbuf   = (unsigned short*)(ws + 262144 + 16777216 + 16777216);

    hipMemsetAsync(counts, 0, 8, stream);
    // blocks [0,2048): transpose tiles; [2048,4096): gating (4 tokens/block)
    prep_kernel<<<4096, 256, 0, stream>>>(x, gw, gb, w1, w2, xb, w1t, w2t,
                                          out, counts, lists, sls);
    // stage 1: bid = m*64 + gin*8 + gch; work (m, g=gch*8+gin); ghosts exit on counts
    moe_gemm<false><<<(NTOK / 64) * 64, 256, 0, stream>>>(xb, w1t, b1, hbuf, nullptr, counts, lists, sls);
    // stage 2: same swizzle; g -> n_idx*4 + e*2 + ksp, split-K=2
    moe_gemm<true><<<(NTOK / 64) * 64, 256, 0, stream>>>(hbuf, w2t, b2, nullptr, out, counts, lists, sls);
}